// Round 4
// baseline (227.774 us; speedup 1.0000x reference)
//
#include <hip/hip_runtime.h>

#define BATCH   262144
#define FIN     128
#define FINP    129            // fan_in + 1 (bias col)
#define FOUT    128
#define NTILES  (BATCH / 16)   // 16384 row-tiles of 16

#define WMAT_BYTES 32768       // 128x128 bf16, swizzled
#define BIAS_OFF   32768       // then 128 f32 bias
#define WS_BYTES   33280

typedef __attribute__((ext_vector_type(8))) short short8;   // 8 bf16 (4 VGPR)
typedef __attribute__((ext_vector_type(4))) float f32x4;    // MFMA C/D

// f32 -> bf16, round-to-nearest-even
__device__ inline unsigned short f2bf(float f) {
    unsigned int u = __float_as_uint(f);
    return (unsigned short)((u + 0x7fffu + ((u >> 16) & 1u)) >> 16);
}

// --- Kernel 1: gather W[hash_idx] once into d_ws (swizzled bf16 Wmat + f32 bias) ---
__global__ __launch_bounds__(256)
void gather_w(const float* __restrict__ W, const int* __restrict__ hidx,
              unsigned char* __restrict__ ws) {
    int t = blockIdx.x * 256 + threadIdx.x;
    if (t < FOUT * FIN) {
        int n = t >> 7;        // fan_out
        int k = t & 127;
        float v = W[hidx[n * FINP + k]];
        unsigned int off = (unsigned)(n * 256 + k * 2) ^ ((unsigned)(n & 7) << 4);
        *(unsigned short*)(ws + off) = f2bf(v);
    } else if (t < FOUT * FIN + FOUT) {
        int n = t - FOUT * FIN;
        *(float*)(ws + BIAS_OFF + n * 4) = W[hidx[n * FINP + FIN]];  // bias, fp32 exact
    }
}

// --- Kernel 2: the GEMM. 512 thr (8 waves), 4 blocks/CU -> 32 waves/CU. ---
__global__ __launch_bounds__(512, 8)
void hashed_mfma(const float* __restrict__ a, const unsigned char* __restrict__ ws,
                 float* __restrict__ out) {
    __shared__ __align__(16) unsigned char lds[WS_BYTES];

    const int tid = threadIdx.x;

    // Coalesced 33 KB copy: ws is L2-resident after the first few blocks.
    for (int t = tid; t < WS_BYTES / 16; t += 512)
        *reinterpret_cast<f32x4*>(lds + t * 16) =
            *reinterpret_cast<const f32x4*>(ws + t * 16);
    __syncthreads();

    const int wave = tid >> 6;  // 0..7
    const int lane = tid & 63;
    const int lr = lane & 15;   // out-row-within-tile
    const int lk = lane >> 4;   // k-group / out-col quad

    // Bias hoisted: lane's 4 output cols per nt are nt*16 + lk*4 .. +3.
    f32x4 biasv[8];
    #pragma unroll
    for (int nt = 0; nt < 8; ++nt)
        biasv[nt] = *reinterpret_cast<const f32x4*>(lds + BIAS_OFF + nt * 64 + lk * 16);

    const int NW = gridDim.x * 8;   // waves in grid
    for (int tile = blockIdx.x * 8 + wave; tile < NTILES; tile += NW) {
        const float* arow = a + (size_t)tile * (16 * FIN);

        // 16x128 fp32 A-tile -> bf16 MFMA B-operand frags (col = lr, 8 consecutive k).
        short8 af[4];
        #pragma unroll
        for (int kk = 0; kk < 4; ++kk) {
            const float* p = arow + lr * FIN + kk * 32 + lk * 8;
            float4 v0 = *reinterpret_cast<const float4*>(p);
            float4 v1 = *reinterpret_cast<const float4*>(p + 4);
            short8 s;
            s[0] = f2bf(v0.x); s[1] = f2bf(v0.y); s[2] = f2bf(v0.z); s[3] = f2bf(v0.w);
            s[4] = f2bf(v1.x); s[5] = f2bf(v1.y); s[6] = f2bf(v1.z); s[7] = f2bf(v1.w);
            af[kk] = s;
        }

        #pragma unroll
        for (int nt = 0; nt < 8; ++nt) {
            const int n = nt * 16 + lr;           // W row (out col block) for this lane
            f32x4 acc = biasv[nt];
            #pragma unroll
            for (int kk = 0; kk < 4; ++kk) {
                unsigned int off = ((unsigned)(n * 256 + kk * 64 + lk * 16))
                                   ^ ((unsigned)(n & 7) << 4);
                short8 wfrag = *reinterpret_cast<const short8*>(lds + off);
                acc = __builtin_amdgcn_mfma_f32_16x16x32_bf16(wfrag, af[kk], acc, 0, 0, 0);
            }
            // Lane holds out[tile*16 + lr][nt*16 + lk*4 .. +3] -> streaming dwordx4.
            f32x4* dst = reinterpret_cast<f32x4*>(out + (size_t)(tile * 16 + lr) * FOUT
                                                      + nt * 16 + lk * 4);
            __builtin_nontemporal_store(acc, dst);
        }
    }
}

extern "C" void kernel_launch(void* const* d_in, const int* in_sizes, int n_in,
                              void* d_out, int out_size, void* d_ws, size_t ws_size,
                              hipStream_t stream) {
    const float* a    = (const float*)d_in[0];
    const float* W    = (const float*)d_in[1];
    const int*   hidx = (const int*)d_in[2];
    float*       out  = (float*)d_out;
    unsigned char* ws = (unsigned char*)d_ws;

    hipLaunchKernelGGL(gather_w, dim3((FOUT * FINP + 255) / 256), dim3(256), 0, stream,
                       W, hidx, ws);
    // 1024 blocks x 512 thr = 4 blocks/CU (132 KB LDS), 32 waves/CU.
    hipLaunchKernelGGL(hashed_mfma, dim3(1024), dim3(512), 0, stream,
                       a, ws, out);
}

// Round 6
// 153.362 us; speedup vs baseline: 1.4852x; 1.4852x over previous
//
#include <hip/hip_runtime.h>

#define BATCH   262144
#define FIN     128
#define FINP    129            // fan_in + 1 (bias col)
#define FOUT    128
#define NTILES  (BATCH / 16)   // 16384 row-tiles of 16

#define BIAS_OFF   32768       // 128x128 bf16 swizzled Wmat, then 128 f32 bias
#define WS_BYTES   33280

typedef __attribute__((ext_vector_type(8))) short short8;   // 8 bf16 (4 VGPR)
typedef __attribute__((ext_vector_type(4))) float f32x4;    // MFMA C/D + 16B ld/st

// f32 -> bf16, round-to-nearest-even
__device__ inline unsigned short f2bf(float f) {
    unsigned int u = __float_as_uint(f);
    return (unsigned short)((u + 0x7fffu + ((u >> 16) & 1u)) >> 16);
}

// --- Kernel 1: gather W[hash_idx] once into d_ws (swizzled bf16 Wmat + f32 bias) ---
__global__ __launch_bounds__(256)
void gather_w(const float* __restrict__ W, const int* __restrict__ hidx,
              unsigned char* __restrict__ ws) {
    int t = blockIdx.x * 256 + threadIdx.x;
    if (t < FOUT * FIN) {
        int n = t >> 7;
        int k = t & 127;
        float v = W[hidx[n * FINP + k]];
        unsigned int off = (unsigned)(n * 256 + k * 2) ^ ((unsigned)(n & 7) << 4);
        *(unsigned short*)(ws + off) = f2bf(v);
    } else if (t < FOUT * FIN + FOUT) {
        int n = t - FOUT * FIN;
        *(float*)(ws + BIAS_OFF + n * 4) = W[hidx[n * FINP + FIN]];  // bias, fp32 exact
    }
}

// --- Kernel 2: GEMM. 256 thr, 4 blocks/CU; pipelined loads + burst NT stores. ---
__global__ __launch_bounds__(256, 4)
void hashed_mfma(const float* __restrict__ a, const unsigned char* __restrict__ ws,
                 float* __restrict__ out) {
    __shared__ __align__(16) unsigned char lds[WS_BYTES];

    const int tid = threadIdx.x;

    for (int t = tid; t < WS_BYTES / 16; t += 256)
        *reinterpret_cast<f32x4*>(lds + t * 16) =
            *reinterpret_cast<const f32x4*>(ws + t * 16);
    __syncthreads();

    const int wave = tid >> 6;
    const int lane = tid & 63;
    const int lr = lane & 15;   // out row within tile
    const int lk = lane >> 4;   // k-group / out-col quad

    const int NW = gridDim.x * 4;   // waves in grid
    int tile = blockIdx.x * 4 + wave;

    // Prologue: first tile's A (16x128 fp32), 8 x 16B per lane, nontemporal.
    f32x4 ar[8];
    {
        const float* p = a + (size_t)tile * (16 * FIN) + lr * FIN + lk * 8;
        #pragma unroll
        for (int kk = 0; kk < 4; ++kk) {
            ar[2 * kk]     = __builtin_nontemporal_load(
                                 reinterpret_cast<const f32x4*>(p + kk * 32));
            ar[2 * kk + 1] = __builtin_nontemporal_load(
                                 reinterpret_cast<const f32x4*>(p + kk * 32 + 4));
        }
    }

    while (tile < NTILES) {
        // Convert current tile to bf16 MFMA B-operand frags (frees ar for prefetch).
        short8 af[4];
        #pragma unroll
        for (int kk = 0; kk < 4; ++kk) {
            f32x4 v0 = ar[2 * kk], v1 = ar[2 * kk + 1];
            short8 s;
            s[0] = f2bf(v0[0]); s[1] = f2bf(v0[1]); s[2] = f2bf(v0[2]); s[3] = f2bf(v0[3]);
            s[4] = f2bf(v1[0]); s[5] = f2bf(v1[1]); s[6] = f2bf(v1[2]); s[7] = f2bf(v1[3]);
            af[kk] = s;
        }

        // Prefetch next tile's A before the MFMA block (latency hides under compute).
        const int next = tile + NW;
        if (next < NTILES) {
            const float* p = a + (size_t)next * (16 * FIN) + lr * FIN + lk * 8;
            #pragma unroll
            for (int kk = 0; kk < 4; ++kk) {
                ar[2 * kk]     = __builtin_nontemporal_load(
                                     reinterpret_cast<const f32x4*>(p + kk * 32));
                ar[2 * kk + 1] = __builtin_nontemporal_load(
                                     reinterpret_cast<const f32x4*>(p + kk * 32 + 4));
            }
        }

        // All 8 n-tiles accumulated before any store.
        f32x4 acc[8];
        #pragma unroll
        for (int nt = 0; nt < 8; ++nt) {
            acc[nt] = *reinterpret_cast<const f32x4*>(lds + BIAS_OFF + nt * 64 + lk * 16);
            const int n = nt * 16 + lr;           // W row (out col block)
            #pragma unroll
            for (int kk = 0; kk < 4; ++kk) {
                unsigned int off = ((unsigned)(n * 256 + kk * 64 + lk * 16))
                                   ^ ((unsigned)(n & 7) << 4);
                short8 wfrag = *reinterpret_cast<const short8*>(lds + off);
                acc[nt] = __builtin_amdgcn_mfma_f32_16x16x32_bf16(wfrag, af[kk], acc[nt], 0, 0, 0);
            }
        }

        // Burst store: row's full 512 B hits the store queue within 8 instructions
        // -> full-line merging, no write-allocate round trip.
        float* orow = out + (size_t)(tile * 16 + lr) * FOUT + lk * 4;
        #pragma unroll
        for (int nt = 0; nt < 8; ++nt)
            __builtin_nontemporal_store(acc[nt], reinterpret_cast<f32x4*>(orow + nt * 16));

        tile = next;
    }
}

extern "C" void kernel_launch(void* const* d_in, const int* in_sizes, int n_in,
                              void* d_out, int out_size, void* d_ws, size_t ws_size,
                              hipStream_t stream) {
    const float* a    = (const float*)d_in[0];
    const float* W    = (const float*)d_in[1];
    const int*   hidx = (const int*)d_in[2];
    float*       out  = (float*)d_out;
    unsigned char* ws = (unsigned char*)d_ws;

    hipLaunchKernelGGL(gather_w, dim3((FOUT * FINP + 255) / 256), dim3(256), 0, stream,
                       W, hidx, ws);
    // 1024 blocks x 256 thr = 4 blocks/CU (132 KB LDS), 16 waves/CU.
    hipLaunchKernelGGL(hashed_mfma, dim3(1024), dim3(256), 0, stream,
                       a, ws, out);
}

// Round 7
// 100.091 us; speedup vs baseline: 2.2757x; 1.5322x over previous
//
#include <hip/hip_runtime.h>

#define BATCH   262144
#define FIN     128
#define FINP    129            // fan_in + 1 (bias col)
#define FOUT    128
#define NT32    (BATCH / 32)   // 8192 row-tiles of 32

#define BIAS_OFF   32768       // 128x128 bf16 swizzled Wmat, then 128 f32 bias
#define WS_BYTES   33280

typedef __attribute__((ext_vector_type(8)))  short short8;   // 8 bf16 (4 VGPR)
typedef __attribute__((ext_vector_type(4)))  float f32x4;
typedef __attribute__((ext_vector_type(16))) float f32x16;   // 32x32 MFMA C/D

// f32 -> bf16, round-to-nearest-even
__device__ inline unsigned short f2bf(float f) {
    unsigned int u = __float_as_uint(f);
    return (unsigned short)((u + 0x7fffu + ((u >> 16) & 1u)) >> 16);
}

// --- Kernel 1: gather W[hash_idx] once into d_ws (swizzled bf16 Wmat + f32 bias) ---
__global__ __launch_bounds__(256)
void gather_w(const float* __restrict__ W, const int* __restrict__ hidx,
              unsigned char* __restrict__ ws) {
    int t = blockIdx.x * 256 + threadIdx.x;
    if (t < FOUT * FIN) {
        int n = t >> 7;
        int k = t & 127;
        float v = W[hidx[n * FINP + k]];
        unsigned int off = (unsigned)(n * 256 + k * 2) ^ ((unsigned)(n & 7) << 4);
        *(unsigned short*)(ws + off) = f2bf(v);
    } else if (t < FOUT * FIN + FOUT) {
        int n = t - FOUT * FIN;
        *(float*)(ws + BIAS_OFF + n * 4) = W[hidx[n * FINP + FIN]];  // bias, fp32 exact
    }
}

// --- Kernel 2: 32x32 MFMA GEMM; full-line dword stores; 512 thr, 33 KB LDS. ---
__global__ __launch_bounds__(512, 6)
void hashed_mfma(const float* __restrict__ a, const unsigned char* __restrict__ ws,
                 float* __restrict__ out) {
    __shared__ __align__(16) unsigned char lds[WS_BYTES];

    const int tid = threadIdx.x;

    for (int t = tid; t < WS_BYTES / 16; t += 512)
        *reinterpret_cast<f32x4*>(lds + t * 16) =
            *reinterpret_cast<const f32x4*>(ws + t * 16);
    __syncthreads();

    const int wave = tid >> 6;     // 0..7
    const int lane = tid & 63;
    const int rt_l = wave >> 2;    // row-tile half of block (0/1)
    const int cb   = wave & 3;     // col-block (32 out cols)
    const int r    = lane & 31;    // batch row within tile (A) / out col (B,C)
    const int hk   = lane >> 5;    // k-half (8 consecutive k)

    // This wave's column bias: same for every acc register (col = cb*32 + r).
    const float bias = *reinterpret_cast<const float*>(lds + BIAS_OFF + (cb * 32 + r) * 4);

    const int n = cb * 32 + r;     // Wmat row (= out col) this lane supplies for B
    // Precompute the 8 swizzled LDS offsets' base: off(kk) = n*256 + (kk*16+hk*8)*2 ^ swz
    const unsigned int swz  = ((unsigned)(n & 7)) << 4;
    const unsigned int wbase = (unsigned)(n * 256 + hk * 16);

    const int stride = gridDim.x * 2;
    for (int t = blockIdx.x * 2 + rt_l; t < NT32; t += stride) {
        const float* arow = a + (size_t)t * (32 * FIN) + (size_t)r * FIN + hk * 8;

        f32x16 acc = {bias, bias, bias, bias, bias, bias, bias, bias,
                      bias, bias, bias, bias, bias, bias, bias, bias};

        #pragma unroll
        for (int kk = 0; kk < 8; ++kk) {
            // A: 8 consecutive f32 of this lane's batch row at k = kk*16 + hk*8.
            f32x4 v0 = *reinterpret_cast<const f32x4*>(arow + kk * 16);
            f32x4 v1 = *reinterpret_cast<const f32x4*>(arow + kk * 16 + 4);
            short8 af;
            af[0] = f2bf(v0[0]); af[1] = f2bf(v0[1]); af[2] = f2bf(v0[2]); af[3] = f2bf(v0[3]);
            af[4] = f2bf(v1[0]); af[5] = f2bf(v1[1]); af[6] = f2bf(v1[2]); af[7] = f2bf(v1[3]);

            // B: Wmat[n][kk*16 + hk*8 .. +7] from swizzled LDS.
            short8 wf = *reinterpret_cast<const short8*>(lds + ((wbase + kk * 32) ^ swz));

            acc = __builtin_amdgcn_mfma_f32_32x32x16_bf16(af, wf, acc, 0, 0, 0);
        }

        // C layout (m74/m101): col = lane&31 (out col), row = (reg&3)+8*(reg>>2)+4*hk.
        // Each dword store: lanes 0..31 / 32..63 each cover a full aligned 128 B line.
        float* obase = out + (size_t)(t * 32 + hk * 4) * FOUT + cb * 32 + r;
        #pragma unroll
        for (int g = 0; g < 4; ++g) {
            #pragma unroll
            for (int q = 0; q < 4; ++q) {
                obase[(size_t)(g * 8 + q) * FOUT] = acc[g * 4 + q];
            }
        }
    }
}

extern "C" void kernel_launch(void* const* d_in, const int* in_sizes, int n_in,
                              void* d_out, int out_size, void* d_ws, size_t ws_size,
                              hipStream_t stream) {
    const float* a    = (const float*)d_in[0];
    const float* W    = (const float*)d_in[1];
    const int*   hidx = (const int*)d_in[2];
    float*       out  = (float*)d_out;
    unsigned char* ws = (unsigned char*)d_ws;

    hipLaunchKernelGGL(gather_w, dim3((FOUT * FINP + 255) / 256), dim3(256), 0, stream,
                       W, hidx, ws);
    // 1024 blocks x 512 thr; 33 KB LDS -> up to 4 blocks/CU; grid-stride over 8192 tiles.
    hipLaunchKernelGGL(hashed_mfma, dim3(1024), dim3(512), 0, stream,
                       a, ws, out);
}

// Round 8
// 51.764 us; speedup vs baseline: 4.4003x; 1.9336x over previous
//
#include <hip/hip_runtime.h>

#define BATCH   262144
#define FIN     128
#define FINP    129            // fan_in + 1 (bias col)
#define FOUT    128
#define NT64    (BATCH / 64)   // 4096 block-iterations of 64 rows

#define BIAS_OFF   32768       // 128x128 bf16 Wmat (row-major, unswizzled), then 128 f32 bias
#define WS_BYTES   33280

typedef __attribute__((ext_vector_type(8)))  short  short8;            // 8 bf16
typedef __attribute__((ext_vector_type(4)))  unsigned short ushort4e;  // 4 bf16 (8 B)
typedef __attribute__((ext_vector_type(4)))  float  f32x4;
typedef __attribute__((ext_vector_type(16))) float  f32x16;            // 32x32 MFMA C/D

// f32 -> bf16, round-to-nearest-even
__device__ inline unsigned short f2bf(float f) {
    unsigned int u = __float_as_uint(f);
    return (unsigned short)((u + 0x7fffu + ((u >> 16) & 1u)) >> 16);
}

// --- Kernel 1: gather W[hash_idx] once into d_ws (row-major bf16 Wmat + f32 bias) ---
__global__ __launch_bounds__(256)
void gather_w(const float* __restrict__ W, const int* __restrict__ hidx,
              unsigned char* __restrict__ ws) {
    int t = blockIdx.x * 256 + threadIdx.x;
    if (t < FOUT * FIN) {
        int n = t >> 7;
        int k = t & 127;
        *(unsigned short*)(ws + n * 256 + k * 2) = f2bf(W[hidx[n * FINP + k]]);
    } else if (t < FOUT * FIN + FOUT) {
        int n = t - FOUT * FIN;
        *(float*)(ws + BIAS_OFF + n * 4) = W[hidx[n * FINP + FIN]];  // bias, fp32 exact
    }
}

// --- Kernel 2: W-in-registers GEMM with LDS-staged A (coalesced, bf16, dbuf). ---
__global__ __launch_bounds__(512, 4)
void hashed_mfma(const float* __restrict__ a, const unsigned char* __restrict__ ws,
                 float* __restrict__ out) {
    // Two 64x128 bf16 A-tiles, rows 256 B, swizzled: byte ^= (row&15)<<4.
    __shared__ __align__(16) unsigned char lds[2][64 * 256];

    const int tid  = threadIdx.x;
    const int wave = tid >> 6;
    const int lane = tid & 63;
    const int rt_l = wave >> 2;    // which 32-row half of the 64-row stage
    const int cb   = wave & 3;     // col-block (32 out cols)
    const int r    = lane & 31;    // batch row within tile (A) / out col (B,C)
    const int hk   = lane >> 5;    // k-half (8 consecutive k)
    const int n    = cb * 32 + r;  // Wmat row = out col for this lane

    // W row held entirely in registers: wf[kk] = Wmat[n][kk*16 + hk*8 .. +7].
    short8 wf[8];
    #pragma unroll
    for (int kk = 0; kk < 8; ++kk)
        wf[kk] = *reinterpret_cast<const short8*>(ws + n * 256 + kk * 32 + hk * 16);
    const float bias = *reinterpret_cast<const float*>(ws + BIAS_OFF + n * 4);

    // Staging map: load i (i=0..3) is global float idx i*2048 + tid*4 of the 64-row
    // chunk -> row = i*16 + (tid>>5), colbyte = (tid&31)*8 in bf16 LDS.
    unsigned int loff[4];
    #pragma unroll
    for (int i = 0; i < 4; ++i) {
        unsigned int row = i * 16 + (tid >> 5);
        loff[i] = (row * 256 + (tid & 31) * 8) ^ ((row & 15) << 4);
    }

    const unsigned int abase = (unsigned)((rt_l * 32 + r) * 256);
    const unsigned int aswz  = ((unsigned)(r & 15)) << 4;

    const f32x4* A4 = reinterpret_cast<const f32x4*>(a);
    const int stride = gridDim.x;
    int it = blockIdx.x;

    // Prologue: issue first chunk's loads (coalesced: 512 lanes x 16 B contiguous).
    f32x4 ar[4];
    #pragma unroll
    for (int i = 0; i < 4; ++i)
        ar[i] = A4[(size_t)it * 2048 + i * 512 + tid];

    int p = 0;
    while (it < NT64) {
        // Convert (16 f2bf/thread, done ONCE per element) + stage into lds[p].
        #pragma unroll
        for (int i = 0; i < 4; ++i) {
            ushort4e b;
            b[0] = f2bf(ar[i][0]); b[1] = f2bf(ar[i][1]);
            b[2] = f2bf(ar[i][2]); b[3] = f2bf(ar[i][3]);
            *reinterpret_cast<ushort4e*>(&lds[p][loff[i]]) = b;
        }

        // Issue next chunk's loads before the barrier (latency hides under compute).
        const int nxt = it + stride;
        if (nxt < NT64) {
            #pragma unroll
            for (int i = 0; i < 4; ++i)
                ar[i] = A4[(size_t)nxt * 2048 + i * 512 + tid];
        }
        __syncthreads();

        // Compute from lds[p]: 8 x (ds_read_b128 A-frag + 32x32x16 MFMA).
        f32x16 acc;
        #pragma unroll
        for (int e = 0; e < 16; ++e) acc[e] = bias;

        const unsigned char* buf = lds[p];
        #pragma unroll
        for (int kk = 0; kk < 8; ++kk) {
            short8 af = *reinterpret_cast<const short8*>(
                buf + ((abase + kk * 32 + hk * 16) ^ aswz));
            acc = __builtin_amdgcn_mfma_f32_32x32x16_bf16(af, wf[kk], acc, 0, 0, 0);
        }

        // C layout: col = lane&31 (out col n), row = (reg&3)+8*(reg>>2)+4*hk.
        // Each dword store covers two full aligned 128 B lines.
        float* obase = out + (size_t)(it * 64 + rt_l * 32 + hk * 4) * FOUT + n;
        #pragma unroll
        for (int g = 0; g < 4; ++g) {
            #pragma unroll
            for (int q = 0; q < 4; ++q)
                obase[(size_t)(g * 8 + q) * FOUT] = acc[g * 4 + q];
        }

        it = nxt;
        p ^= 1;
    }
}

extern "C" void kernel_launch(void* const* d_in, const int* in_sizes, int n_in,
                              void* d_out, int out_size, void* d_ws, size_t ws_size,
                              hipStream_t stream) {
    const float* a    = (const float*)d_in[0];
    const float* W    = (const float*)d_in[1];
    const int*   hidx = (const int*)d_in[2];
    float*       out  = (float*)d_out;
    unsigned char* ws = (unsigned char*)d_ws;

    hipLaunchKernelGGL(gather_w, dim3((FOUT * FINP + 255) / 256), dim3(256), 0, stream,
                       W, hidx, ws);
    // 1024 blocks x 512 thr; 32 KB LDS -> 4 blocks/CU; 4 iterations/block.
    hipLaunchKernelGGL(hashed_mfma, dim3(1024), dim3(512), 0, stream,
                       a, ws, out);
}

// Round 9
// 51.737 us; speedup vs baseline: 4.4026x; 1.0005x over previous
//
#include <hip/hip_runtime.h>

#define BATCH   262144
#define FIN     128
#define FINP    129            // fan_in + 1 (bias col)
#define FOUT    128
#define NT64    (BATCH / 64)   // 4096 block-iterations of 64 rows

#define BIAS_OFF   32768       // 128x128 bf16 Wmat (row-major), then 128 f32 bias
#define WS_BYTES   33280

typedef __attribute__((ext_vector_type(8)))  short  short8;            // 8 bf16
typedef __attribute__((ext_vector_type(4)))  unsigned short ushort4e;  // 4 bf16 (8 B)
typedef __attribute__((ext_vector_type(4)))  float  f32x4;
typedef __attribute__((ext_vector_type(16))) float  f32x16;            // 32x32 MFMA C/D

// f32 -> bf16, round-to-nearest-even
__device__ inline unsigned short f2bf(float f) {
    unsigned int u = __float_as_uint(f);
    return (unsigned short)((u + 0x7fffu + ((u >> 16) & 1u)) >> 16);
}

// --- Kernel 1: gather W[hash_idx] once into d_ws (row-major bf16 Wmat + f32 bias) ---
__global__ __launch_bounds__(256)
void gather_w(const float* __restrict__ W, const int* __restrict__ hidx,
              unsigned char* __restrict__ ws) {
    int t = blockIdx.x * 256 + threadIdx.x;
    if (t < FOUT * FIN) {
        int n = t >> 7;
        int k = t & 127;
        *(unsigned short*)(ws + n * 256 + k * 2) = f2bf(W[hidx[n * FINP + k]]);
    } else if (t < FOUT * FIN + FOUT) {
        int n = t - FOUT * FIN;
        *(float*)(ws + BIAS_OFF + n * 4) = W[hidx[n * FINP + FIN]];  // bias, fp32 exact
    }
}

// --- Kernel 2: W-in-registers GEMM, LDS-staged A; prefetch issued AFTER the barrier
//     so the s_barrier's vmcnt(0) drain cannot serialize it against compute. ---
__global__ __launch_bounds__(512, 4)
void hashed_mfma(const float* __restrict__ a, const unsigned char* __restrict__ ws,
                 float* __restrict__ out) {
    // Two 64x128 bf16 A-tiles, rows 256 B, swizzled: byte ^= (row&15)<<4.
    __shared__ __align__(16) unsigned char lds[2][64 * 256];

    const int tid  = threadIdx.x;
    const int wave = tid >> 6;
    const int lane = tid & 63;
    const int rt_l = wave >> 2;    // which 32-row half of the 64-row stage
    const int cb   = wave & 3;     // col-block (32 out cols)
    const int r    = lane & 31;    // batch row within tile (A) / out col (B,C)
    const int hk   = lane >> 5;    // k-half (8 consecutive k)
    const int n    = cb * 32 + r;  // Wmat row = out col for this lane

    // W row held entirely in registers: wf[kk] = Wmat[n][kk*16 + hk*8 .. +7].
    short8 wf[8];
    #pragma unroll
    for (int kk = 0; kk < 8; ++kk)
        wf[kk] = *reinterpret_cast<const short8*>(ws + n * 256 + kk * 32 + hk * 16);
    const float bias = *reinterpret_cast<const float*>(ws + BIAS_OFF + n * 4);

    // Staging map: load i (i=0..3) is global float idx i*2048 + tid*4 of the 64-row
    // chunk -> row = i*16 + (tid>>5), colbyte = (tid&31)*8 in bf16 LDS.
    unsigned int loff[4];
    #pragma unroll
    for (int i = 0; i < 4; ++i) {
        unsigned int row = i * 16 + (tid >> 5);
        loff[i] = (row * 256 + (tid & 31) * 8) ^ ((row & 15) << 4);
    }

    const unsigned int abase = (unsigned)((rt_l * 32 + r) * 256);
    const unsigned int aswz  = ((unsigned)(r & 15)) << 4;

    const f32x4* A4 = reinterpret_cast<const f32x4*>(a);
    const int stride = gridDim.x;
    int it = blockIdx.x;

    // Prologue: first chunk's loads (coalesced: 512 lanes x 16 B contiguous).
    f32x4 ar[4];
    #pragma unroll
    for (int i = 0; i < 4; ++i)
        ar[i] = A4[(size_t)it * 2048 + i * 512 + tid];

    int p = 0;
    while (it < NT64) {
        // Convert (waits vmcnt for the loads; older stores may still be in flight)
        // and stage into lds[p].
        #pragma unroll
        for (int i = 0; i < 4; ++i) {
            ushort4e b;
            b[0] = f2bf(ar[i][0]); b[1] = f2bf(ar[i][1]);
            b[2] = f2bf(ar[i][2]); b[3] = f2bf(ar[i][3]);
            *reinterpret_cast<ushort4e*>(&lds[p][loff[i]]) = b;
        }

        __syncthreads();

        // Prefetch the NEXT chunk now — after the barrier, so the barrier's
        // vmcnt(0) drain didn't touch it; latency hides under compute + stores.
        const int nxt = it + stride;
        if (nxt < NT64) {
            #pragma unroll
            for (int i = 0; i < 4; ++i)
                ar[i] = A4[(size_t)nxt * 2048 + i * 512 + tid];
        }

        // Compute from lds[p]: 8 x (ds_read_b128 A-frag + 32x32x16 MFMA).
        f32x16 acc;
        #pragma unroll
        for (int e = 0; e < 16; ++e) acc[e] = bias;

        const unsigned char* buf = lds[p];
        #pragma unroll
        for (int kk = 0; kk < 8; ++kk) {
            short8 af = *reinterpret_cast<const short8*>(
                buf + ((abase + kk * 32 + hk * 16) ^ aswz));
            acc = __builtin_amdgcn_mfma_f32_32x32x16_bf16(af, wf[kk], acc, 0, 0, 0);
        }

        // C layout: col = lane&31 (out col n), row = (reg&3)+8*(reg>>2)+4*hk.
        // Each dword store covers two full aligned 128 B lines.
        float* obase = out + (size_t)(it * 64 + rt_l * 32 + hk * 4) * FOUT + n;
        #pragma unroll
        for (int g = 0; g < 4; ++g) {
            #pragma unroll
            for (int q = 0; q < 4; ++q)
                obase[(size_t)(g * 8 + q) * FOUT] = acc[g * 4 + q];
        }

        it = nxt;
        p ^= 1;
    }
}

extern "C" void kernel_launch(void* const* d_in, const int* in_sizes, int n_in,
                              void* d_out, int out_size, void* d_ws, size_t ws_size,
                              hipStream_t stream) {
    const float* a    = (const float*)d_in[0];
    const float* W    = (const float*)d_in[1];
    const int*   hidx = (const int*)d_in[2];
    float*       out  = (float*)d_out;
    unsigned char* ws = (unsigned char*)d_ws;

    hipLaunchKernelGGL(gather_w, dim3((FOUT * FINP + 255) / 256), dim3(256), 0, stream,
                       W, hidx, ws);
    // 1024 blocks x 512 thr; 32 KB LDS -> 4 blocks/CU resident; 4 iterations/block.
    hipLaunchKernelGGL(hashed_mfma, dim3(1024), dim3(512), 0, stream,
                       a, ws, out);
}